// Round 6
// baseline (522.734 us; speedup 1.0000x reference)
//
#include <hip/hip_runtime.h>
#include <math.h>

// Problem constants (fixed-shape: B=8, T=2048, C=1024, fp32 in/out)
#define B_DIM 8
#define T_DIM 2048
#define C_DIM 1024
#define BT_DIM (B_DIM * T_DIM)                 // 16384 rows
#define FSZ ((size_t)BT_DIM * C_DIM)           // 16,777,216 elements per [B,T,C]
#define LN_EPS 1e-5f

typedef __bf16 bf16x8 __attribute__((ext_vector_type(8)));
typedef _Float16 f16x8 __attribute__((ext_vector_type(8)));
typedef float f32x4 __attribute__((ext_vector_type(4)));

__device__ __forceinline__ unsigned short f2bf(float f) {
  __bf16 h = (__bf16)f;
  return __builtin_bit_cast(unsigned short, h);
}
__device__ __forceinline__ unsigned short f2h(float f) {
  _Float16 h = (_Float16)f;
  return __builtin_bit_cast(unsigned short, h);
}
__device__ __forceinline__ float bf2f(unsigned short u) {
  unsigned int v = ((unsigned int)u) << 16;
  return __builtin_bit_cast(float, v);
}

// async global->LDS, 16 B per lane. LDS dest must be wave-uniform base + lane*16.
__device__ __forceinline__ void gld16(const void* g, void* l) {
  __builtin_amdgcn_global_load_lds(
      (const __attribute__((address_space(1))) unsigned int*)g,
      (__attribute__((address_space(3))) unsigned int*)l, 16, 0, 0);
}

// LDS bank swizzle for float2 arrays: bank-pair = idx mod 16. XOR low 4 bits
// with a hash of higher bits -> butterfly strides {512,128,32,8,2} land on
// distinct bank pairs; contiguous access stays conflict-free (in-block perm).
__device__ __forceinline__ int swz(int a) {
  return a ^ (((a >> 4) ^ (a >> 8)) & 15);
}

// digit-reversal map of the radix-4^5 x 2 DIF: frequency f -> storage pos.
__device__ __forceinline__ int enc11(int f) {
  return ((f & 3) << 9) | (((f >> 2) & 3) << 7) | (((f >> 4) & 3) << 5) |
         (((f >> 6) & 3) << 3) | (((f >> 8) & 3) << 1) | ((f >> 10) & 1);
}

// ---------------------------------------------------------------------------
// FUSED: x fp32 -> (hi, lo) f16 split  AND  sv[r] = dot(x[r,:], wvsum)+bvsum.
// ---------------------------------------------------------------------------
__global__ __launch_bounds__(256)
void cvt_split_sv_kernel(const float* __restrict__ x, const float* __restrict__ wvsum,
                         const float* __restrict__ bvsum,
                         unsigned short* __restrict__ hi, unsigned short* __restrict__ lo,
                         float* __restrict__ sv) {
  const int r = blockIdx.x;
  const int tid = threadIdx.x;
  const size_t base = (size_t)r * C_DIM + (tid << 2);
  float4 v = *(const float4*)(x + base);
  float4 w = *(const float4*)(wvsum + (tid << 2));
  float f[4] = {v.x, v.y, v.z, v.w};
  unsigned short hv[4], lv[4];
#pragma unroll
  for (int i = 0; i < 4; i++) {
    _Float16 hb = (_Float16)f[i];
    hv[i] = __builtin_bit_cast(unsigned short, hb);
    lv[i] = f2h(f[i] - (float)hb);
  }
  *(ushort4*)(hi + base) = make_ushort4(hv[0], hv[1], hv[2], hv[3]);
  *(ushort4*)(lo + base) = make_ushort4(lv[0], lv[1], lv[2], lv[3]);
  float s = v.x * w.x + v.y * w.y + v.z * w.z + v.w * w.w;
#pragma unroll
  for (int off = 32; off > 0; off >>= 1) s += __shfl_down(s, off);
  __shared__ float ps[4];
  if ((tid & 63) == 0) ps[tid >> 6] = s;
  __syncthreads();
  if (tid == 0) sv[r] = ps[0] + ps[1] + ps[2] + ps[3] + bvsum[0];
}

// ---------------------------------------------------------------------------
// W [K,N] fp32 -> Wt [N,K] f16. 32x32 LDS tiles.
// ---------------------------------------------------------------------------
__global__ __launch_bounds__(256)
void wtrans_f16_kernel(const float* __restrict__ W, unsigned short* __restrict__ Wt,
                       int K, int N) {
  __shared__ float tile[32][33];
  const int tid = threadIdx.x;
  const int tx = tid & 31, ty = tid >> 5;
  const int n0 = blockIdx.x * 32, k0 = blockIdx.y * 32;
#pragma unroll
  for (int i = 0; i < 4; i++) {
    int row = ty + i * 8;
    tile[row][tx] = W[(size_t)(k0 + row) * N + n0 + tx];
  }
  __syncthreads();
#pragma unroll
  for (int i = 0; i < 4; i++) {
    int row = ty + i * 8;
    Wt[(size_t)(n0 + row) * K + k0 + tx] = f2h(tile[tx][row]);
  }
}

// ---------------------------------------------------------------------------
// W [K,N] fp32 -> Wt [N,K] bf16. For the FFN weights.
// ---------------------------------------------------------------------------
__global__ __launch_bounds__(256)
void wtrans_kernel(const float* __restrict__ W, unsigned short* __restrict__ Wt,
                   int K, int N) {
  __shared__ float tile[32][33];
  const int tid = threadIdx.x;
  const int tx = tid & 31, ty = tid >> 5;
  const int n0 = blockIdx.x * 32, k0 = blockIdx.y * 32;
#pragma unroll
  for (int i = 0; i < 4; i++) {
    int row = ty + i * 8;
    tile[row][tx] = W[(size_t)(k0 + row) * N + n0 + tx];
  }
  __syncthreads();
#pragma unroll
  for (int i = 0; i < 4; i++) {
    int row = ty + i * 8;
    Wt[(size_t)(n0 + row) * K + k0 + tx] = f2bf(tile[tx][row]);
  }
}

// ---------------------------------------------------------------------------
// wvsum[k] = sum_n Wv[k,n]  (blocks 0..K-1); block K reduces bv -> bvsum.
// ---------------------------------------------------------------------------
__global__ __launch_bounds__(256)
void wv_rowsum_kernel(const float* __restrict__ Wv, const float* __restrict__ bv,
                      float* __restrict__ wvsum, float* __restrict__ bvsum) {
  const int r = blockIdx.x;
  const int tid = threadIdx.x;
  const float* src = (r < C_DIM) ? (Wv + (size_t)r * C_DIM) : bv;
  float4 t4 = *(const float4*)(src + (tid << 2));
  float s = t4.x + t4.y + t4.z + t4.w;
#pragma unroll
  for (int off = 32; off > 0; off >>= 1) s += __shfl_down(s, off);
  __shared__ float ps[4];
  if ((tid & 63) == 0) ps[tid >> 6] = s;
  __syncthreads();
  if (tid == 0) {
    float v = ps[0] + ps[1] + ps[2] + ps[3];
    if (r < C_DIM) wvsum[r] = v; else bvsum[0] = v;
  }
}

// ---------------------------------------------------------------------------
// FFN bf16 GEMM, PORTED to the proven qkT 256x128 4-phase structure:
// Y[M,N](bf16) = A[M,K](bf16) @ Bt[N,K]^T + bias, optional relu.
// Single stream each side -> 3 gld16/thread/tile, vmcnt(3), 72 KB 3-ring ->
// __launch_bounds__(512,4) allows 2 blocks/CU (barrier stalls overlap across
// blocks -- the axis the 144 KB qkT kernel cannot use). Addressing, swizzle,
// per-phase barrier schedule and C/D mapping identical to the verified qkT.
// ---------------------------------------------------------------------------
__global__ __launch_bounds__(512, 4)
void gemm_bf16_8ph_kernel(const __bf16* __restrict__ A, const __bf16* __restrict__ Bt,
                          const float* __restrict__ bias, unsigned short* __restrict__ Yb,
                          int K, int N, int do_relu) {
  __shared__ __align__(16) __bf16 AsL[3][256 * 32];
  __shared__ __align__(16) __bf16 BsL[3][128 * 32];

  const int tid = threadIdx.x;
  const int wave = tid >> 6, lane = tid & 63;
  const int wr = wave >> 2, wc = wave & 3;          // 2 x 4 wave grid
  const int r15 = lane & 15, kq = lane >> 4;
  // grid (8,64): hw id = bx + 8*by; xcd = id&7. Bijective remap.
  const int h = blockIdx.y * 8 + blockIdx.x;
  const int xcd = h & 7, s = h >> 3;
  const int mIdx = (xcd << 3) + (s & 3) + ((s >> 5) << 2);
  const int nIdx = (s >> 2) & 7;
  const int m0 = mIdx * 256, n0 = nIdx * 128;
  const int NT = K >> 5;                            // 32 K-tiles of BK=32

  // --- staging descriptors (identical to qkT) ---
  const int row_a0 = tid >> 2;                      // 0..127
  const int row_a1 = row_a0 + 128;                  // 128..255
  const int ch = tid & 3;
  const int ko0 = ch ^ ((row_a0 >> 1) & 3);
  const int ko1 = ch ^ ((row_a1 >> 1) & 3);
  const __bf16* ag0 = A  + (size_t)(m0 + row_a0) * K + ko0 * 8;
  const __bf16* ag1 = A  + (size_t)(m0 + row_a1) * K + ko1 * 8;
  const __bf16* bg  = Bt + (size_t)(n0 + row_a0) * K + ko0 * 8;

  // --- fragment read offsets (identical to qkT) ---
  const int ksel = kq ^ ((r15 >> 1) & 3);
  const int aoff = (wr * 128 + r15) * 32 + ksel * 8;   // + mi*512
  const int boff = (wc * 32 + r15) * 32 + ksel * 8;    // + ni*512

  f32x4 acc[8][2] = {};

  // --- prologue: stage tile 0 -> buf0, tile 1 -> buf1 (3 loads each) ---
  gld16(ag0 + 0, &AsL[0][(size_t)tid * 8]);
  gld16(ag1 + 0, &AsL[0][(size_t)(tid + 512) * 8]);
  gld16(bg + 0, &BsL[0][(size_t)tid * 8]);
  gld16(ag0 + 32, &AsL[1][(size_t)tid * 8]);
  gld16(ag1 + 32, &AsL[1][(size_t)(tid + 512) * 8]);
  gld16(bg + 32, &BsL[1][(size_t)tid * 8]);

  int bR = 0;  // read buffer = j % 3
  int bS = 2;  // stage buffer = (j+2) % 3

  for (int j = 0; j < NT; ++j) {
    // Tile-j data ready: newest 3 outstanding loads belong to tile j+1.
    if (j < NT - 1) {
      asm volatile("s_waitcnt vmcnt(3)" ::: "memory");
    } else {
      asm volatile("s_waitcnt vmcnt(0)" ::: "memory");
    }
    __builtin_amdgcn_s_barrier();
    __builtin_amdgcn_sched_barrier(0);

    const int kk = (j + 2) * 32;
    const bool doStage = (j + 2 < NT);

    // B fragments for the whole tile
    bf16x8 bf[2];
#pragma unroll
    for (int ni = 0; ni < 2; ++ni)
      bf[ni] = *(const bf16x8*)&BsL[bR][boff + ni * 512];

#pragma unroll
    for (int p = 0; p < 4; ++p) {
      bf16x8 a0 = *(const bf16x8*)&AsL[bR][aoff + (2 * p + 0) * 512];
      bf16x8 a1 = *(const bf16x8*)&AsL[bR][aoff + (2 * p + 1) * 512];
      if (doStage) {
        if (p == 0) gld16(ag0 + kk, &AsL[bS][(size_t)tid * 8]);
        if (p == 1) gld16(ag1 + kk, &AsL[bS][(size_t)(tid + 512) * 8]);
        if (p == 2) gld16(bg + kk, &BsL[bS][(size_t)tid * 8]);
      }
      __builtin_amdgcn_s_barrier();                       // phase alignment
      asm volatile("s_waitcnt lgkmcnt(0)" ::: "memory");  // own ds_reads done
      __builtin_amdgcn_sched_barrier(0);                  // rule 18
      __builtin_amdgcn_s_setprio(1);
#pragma unroll
      for (int m2 = 0; m2 < 2; ++m2) {
        const int mi = 2 * p + m2;
        const bf16x8 av = m2 ? a1 : a0;
#pragma unroll
        for (int ni = 0; ni < 2; ++ni)
          acc[mi][ni] = __builtin_amdgcn_mfma_f32_16x16x32_bf16(av, bf[ni], acc[mi][ni], 0, 0, 0);
      }
      __builtin_amdgcn_s_setprio(0);
      __builtin_amdgcn_sched_barrier(0);
    }

    bR = (bR + 1 == 3) ? 0 : bR + 1;
    bS = (bS + 1 == 3) ? 0 : bS + 1;
  }

  // --- epilogue: bias (+relu) + bf16 stores, row-major [M,N] ---
  float bv[2];
#pragma unroll
  for (int ni = 0; ni < 2; ++ni) bv[ni] = bias[n0 + wc * 32 + ni * 16 + r15];

#pragma unroll
  for (int mi = 0; mi < 8; ++mi) {
    const int mbase = m0 + wr * 128 + mi * 16 + kq * 4;
#pragma unroll
    for (int ni = 0; ni < 2; ++ni) {
      const int n = n0 + wc * 32 + ni * 16 + r15;
#pragma unroll
      for (int r = 0; r < 4; ++r) {
        float v = acc[mi][ni][r] + bv[ni];
        if (do_relu) v = fmaxf(v, 0.f);
        Yb[(size_t)(mbase + r) * N + n] = f2bf(v);
      }
    }
  }
}

// ---------------------------------------------------------------------------
// FUSED q+k split-f16 GEMM with TRANSPOSED outputs: Yq/Yk [B,C,T] fp32.
// ROUND-4 VERSION RESTORED (139.5 us, MfmaUtil 43, conflicts 0): 4-phase
// per-phase-barrier schedule. r5 (no barriers) regressed to 156 us — the
// per-phase barriers ENFORCE the ds_read||stage||MFMA interleave (m196).
// ---------------------------------------------------------------------------
__global__ __launch_bounds__(512, 2)
void gemm_qkT_f16_8ph_kernel(const _Float16* __restrict__ Ahi, const _Float16* __restrict__ Alo,
                             const _Float16* __restrict__ Bq, const _Float16* __restrict__ Bk,
                             const float* __restrict__ biasq, const float* __restrict__ biask,
                             float* __restrict__ Yq, float* __restrict__ Yk, int K, int N) {
  // 3-ring LDS: (16+16+8+8) KB * 3 = 144 KB -> 1 block/CU
  __shared__ __align__(16) _Float16 AhL[3][256 * 32];
  __shared__ __align__(16) _Float16 AlL[3][256 * 32];
  __shared__ __align__(16) _Float16 BqL[3][128 * 32];
  __shared__ __align__(16) _Float16 BkL[3][128 * 32];

  const int tid = threadIdx.x;
  const int wave = tid >> 6, lane = tid & 63;
  const int wr = wave >> 2, wc = wave & 3;          // 2 x 4 wave grid
  const int r15 = lane & 15, kq = lane >> 4;
  // grid (8,64): hw id = bx + 8*by; xcd = id&7. Bijective remap.
  const int h = blockIdx.y * 8 + blockIdx.x;
  const int xcd = h & 7, s = h >> 3;
  const int mIdx = (xcd << 3) + (s & 3) + ((s >> 5) << 2);
  const int nIdx = (s >> 2) & 7;
  const int m0 = mIdx * 256, n0 = nIdx * 128;
  const int NT = K >> 5;                            // 32 K-tiles of BK=32

  // --- staging descriptors ---
  const int row_a0 = tid >> 2;                      // 0..127
  const int row_a1 = row_a0 + 128;                  // 128..255
  const int ch = tid & 3;
  const int ko0 = ch ^ ((row_a0 >> 1) & 3);
  const int ko1 = ch ^ ((row_a1 >> 1) & 3);
  const _Float16* agh0 = Ahi + (size_t)(m0 + row_a0) * K + ko0 * 8;
  const _Float16* agl0 = Alo + (size_t)(m0 + row_a0) * K + ko0 * 8;
  const _Float16* agh1 = Ahi + (size_t)(m0 + row_a1) * K + ko1 * 8;
  const _Float16* agl1 = Alo + (size_t)(m0 + row_a1) * K + ko1 * 8;
  const _Float16* bgq  = Bq  + (size_t)(n0 + row_a0) * K + ko0 * 8;
  const _Float16* bgk  = Bk  + (size_t)(n0 + row_a0) * K + ko0 * 8;

  // --- fragment read offsets ---
  const int ksel = kq ^ ((r15 >> 1) & 3);
  const int aoff = (wr * 128 + r15) * 32 + ksel * 8;   // + mi*512
  const int boff = (wc * 32 + r15) * 32 + ksel * 8;    // + ni*512

  f32x4 accq[8][2] = {};
  f32x4 acck[8][2] = {};

  // --- prologue: stage tile 0 -> buf0, tile 1 -> buf1 (6 loads each) ---
  gld16(agh0 + 0, &AhL[0][(size_t)tid * 8]);
  gld16(agl0 + 0, &AlL[0][(size_t)tid * 8]);
  gld16(agh1 + 0, &AhL[0][(size_t)(tid + 512) * 8]);
  gld16(agl1 + 0, &AlL[0][(size_t)(tid + 512) * 8]);
  gld16(bgq + 0, &BqL[0][(size_t)tid * 8]);
  gld16(bgk + 0, &BkL[0][(size_t)tid * 8]);
  gld16(agh0 + 32, &AhL[1][(size_t)tid * 8]);
  gld16(agl0 + 32, &AlL[1][(size_t)tid * 8]);
  gld16(agh1 + 32, &AhL[1][(size_t)(tid + 512) * 8]);
  gld16(agl1 + 32, &AlL[1][(size_t)(tid + 512) * 8]);
  gld16(bgq + 32, &BqL[1][(size_t)tid * 8]);
  gld16(bgk + 32, &BkL[1][(size_t)tid * 8]);

  int bR = 0;  // read buffer = j % 3
  int bS = 2;  // stage buffer = (j+2) % 3

  for (int j = 0; j < NT; ++j) {
    // Tile-j data ready: newest 6 outstanding loads belong to tile j+1.
    if (j < NT - 1) {
      asm volatile("s_waitcnt vmcnt(6)" ::: "memory");
    } else {
      asm volatile("s_waitcnt vmcnt(0)" ::: "memory");
    }
    __builtin_amdgcn_s_barrier();
    __builtin_amdgcn_sched_barrier(0);

    const int kk = (j + 2) * 32;
    const bool doStage = (j + 2 < NT);

    // B fragments for the whole tile (phase 0 ds-reads)
    f16x8 bqf[2], bkf[2];
#pragma unroll
    for (int ni = 0; ni < 2; ++ni) {
      bqf[ni] = *(const f16x8*)&BqL[bR][boff + ni * 512];
      bkf[ni] = *(const f16x8*)&BkL[bR][boff + ni * 512];
    }

#pragma unroll
    for (int p = 0; p < 4; ++p) {
      f16x8 ah0 = *(const f16x8*)&AhL[bR][aoff + (2 * p + 0) * 512];
      f16x8 al0 = *(const f16x8*)&AlL[bR][aoff + (2 * p + 0) * 512];
      f16x8 ah1 = *(const f16x8*)&AhL[bR][aoff + (2 * p + 1) * 512];
      f16x8 al1 = *(const f16x8*)&AlL[bR][aoff + (2 * p + 1) * 512];
      if (doStage) {
        if (p == 0) {
          gld16(agh0 + kk, &AhL[bS][(size_t)tid * 8]);
          gld16(agl0 + kk, &AlL[bS][(size_t)tid * 8]);
        }
        if (p == 1) {
          gld16(agh1 + kk, &AhL[bS][(size_t)(tid + 512) * 8]);
          gld16(agl1 + kk, &AlL[bS][(size_t)(tid + 512) * 8]);
        }
        if (p == 2) gld16(bgq + kk, &BqL[bS][(size_t)tid * 8]);
        if (p == 3) gld16(bgk + kk, &BkL[bS][(size_t)tid * 8]);
      }
      __builtin_amdgcn_s_barrier();                       // phase alignment
      asm volatile("s_waitcnt lgkmcnt(0)" ::: "memory");  // own ds_reads done
      __builtin_amdgcn_sched_barrier(0);                  // rule 18: pin MFMA below
      __builtin_amdgcn_s_setprio(1);
#pragma unroll
      for (int m2 = 0; m2 < 2; ++m2) {
        const int mi = 2 * p + m2;
        const f16x8 ahv = m2 ? ah1 : ah0;
        const f16x8 alv = m2 ? al1 : al0;
#pragma unroll
        for (int ni = 0; ni < 2; ++ni) {
          accq[mi][ni] = __builtin_amdgcn_mfma_f32_16x16x32_f16(ahv, bqf[ni], accq[mi][ni], 0, 0, 0);
          accq[mi][ni] = __builtin_amdgcn_mfma_f32_16x16x32_f16(alv, bqf[ni], accq[mi][ni], 0, 0, 0);
          acck[mi][ni] = __builtin_amdgcn_mfma_f32_16x16x32_f16(ahv, bkf[ni], acck[mi][ni], 0, 0, 0);
          acck[mi][ni] = __builtin_amdgcn_mfma_f32_16x16x32_f16(alv, bkf[ni], acck[mi][ni], 0, 0, 0);
        }
      }
      __builtin_amdgcn_s_setprio(0);
      __builtin_amdgcn_sched_barrier(0);
    }

    bR = (bR + 1 == 3) ? 0 : bR + 1;
    bS = (bS + 1 == 3) ? 0 : bS + 1;
  }

  // --- epilogue: bias + transposed float4 stores ---
  float bvq[2], bvk[2];
#pragma unroll
  for (int ni = 0; ni < 2; ++ni) {
    bvq[ni] = biasq[n0 + wc * 32 + ni * 16 + r15];
    bvk[ni] = biask[n0 + wc * 32 + ni * 16 + r15];
  }

#pragma unroll
  for (int mi = 0; mi < 8; ++mi) {
    const int mbase = m0 + wr * 128 + mi * 16 + kq * 4;  // 4 consecutive m
    const int bb = mbase >> 11;                          // batch (T=2048)
    const int t = mbase & (T_DIM - 1);
#pragma unroll
    for (int ni = 0; ni < 2; ++ni) {
      const int n = n0 + wc * 32 + ni * 16 + r15;
      const size_t o = ((size_t)bb * C_DIM + n) * T_DIM + t;
      *(float4*)(Yq + o) = make_float4(accq[mi][ni][0] + bvq[ni], accq[mi][ni][1] + bvq[ni],
                                       accq[mi][ni][2] + bvq[ni], accq[mi][ni][3] + bvq[ni]);
      *(float4*)(Yk + o) = make_float4(acck[mi][ni][0] + bvk[ni], acck[mi][ni][1] + bvk[ni],
                                       acck[mi][ni][2] + bvk[ni], acck[mi][ni][3] + bvk[ni]);
    }
  }
}

// ---------------------------------------------------------------------------
// In-place 2048-pt FFT, radix-4 DIF (5 stages) + radix-2.
// ---------------------------------------------------------------------------
__device__ void fft_dif(float2* X, const float2* tw, int tid, float sgn) {
#pragma unroll
  for (int s = 0; s < 5; s++) {
    const int m = 512 >> (2 * s);
    const int jstep = 512 / m;  // 4^s
#pragma unroll
    for (int ii = 0; ii < 2; ii++) {
      const int i = tid + ii * 256;
      const int q = i & (m - 1);
      const int a0 = ((i - q) << 2) + q;
      float2 x0 = X[swz(a0)];
      float2 x1 = X[swz(a0 + m)];
      float2 x2 = X[swz(a0 + 2 * m)];
      float2 x3 = X[swz(a0 + 3 * m)];
      float2 t0 = make_float2(x0.x + x2.x, x0.y + x2.y);
      float2 t2 = make_float2(x0.x - x2.x, x0.y - x2.y);
      float2 t1 = make_float2(x1.x + x3.x, x1.y + x3.y);
      float2 t3 = make_float2(x1.x - x3.x, x1.y - x3.y);
      const float jx = -sgn * t3.y, jy = sgn * t3.x;   // sgn*i*t3
      float2 y0 = make_float2(t0.x + t1.x, t0.y + t1.y);
      float2 y1 = make_float2(t2.x + jx, t2.y + jy);
      float2 y2 = make_float2(t0.x - t1.x, t0.y - t1.y);
      float2 y3 = make_float2(t2.x - jx, t2.y - jy);
      const int j1 = q * jstep;
      float2 tv = tw[swz(j1)];
      const float c1 = tv.x, s1 = tv.y * sgn;
      const float c2 = c1 * c1 - s1 * s1, s2 = 2.f * c1 * s1;
      const float c3 = c2 * c1 - s2 * s1, s3 = c2 * s1 + s2 * c1;
      X[swz(a0)] = y0;
      X[swz(a0 + m)] = make_float2(c1 * y1.x - s1 * y1.y, c1 * y1.y + s1 * y1.x);
      X[swz(a0 + 2 * m)] = make_float2(c2 * y2.x - s2 * y2.y, c2 * y2.y + s2 * y2.x);
      X[swz(a0 + 3 * m)] = make_float2(c3 * y3.x - s3 * y3.y, c3 * y3.y + s3 * y3.x);
    }
    __syncthreads();
  }
  // final radix-2 on adjacent pairs, twiddle-free
#pragma unroll
  for (int ii = 0; ii < 4; ii++) {
    const int a = (tid + ii * 256) << 1;
    float2 u = X[swz(a)], v = X[swz(a + 1)];
    X[swz(a)] = make_float2(u.x + v.x, u.y + v.y);
    X[swz(a + 1)] = make_float2(u.x - v.x, u.y - v.y);
  }
  __syncthreads();
}

// In-place inverse (adjoint of fft_dif, unnormalized).
__device__ void fft_dit_inv(float2* X, const float2* tw, int tid) {
#pragma unroll
  for (int ii = 0; ii < 4; ii++) {
    const int a = (tid + ii * 256) << 1;
    float2 u = X[swz(a)], v = X[swz(a + 1)];
    X[swz(a)] = make_float2(u.x + v.x, u.y + v.y);
    X[swz(a + 1)] = make_float2(u.x - v.x, u.y - v.y);
  }
  __syncthreads();
#pragma unroll
  for (int s = 4; s >= 0; s--) {
    const int m = 512 >> (2 * s);
    const int jstep = 512 / m;
#pragma unroll
    for (int ii = 0; ii < 2; ii++) {
      const int i = tid + ii * 256;
      const int q = i & (m - 1);
      const int a0 = ((i - q) << 2) + q;
      float2 v0 = X[swz(a0)];
      float2 v1 = X[swz(a0 + m)];
      float2 v2 = X[swz(a0 + 2 * m)];
      float2 v3 = X[swz(a0 + 3 * m)];
      const int j1 = q * jstep;
      float2 tv = tw[swz(j1)];
      const float c1 = tv.x, s1 = tv.y;  // e^{+i theta}
      const float c2 = c1 * c1 - s1 * s1, s2 = 2.f * c1 * s1;
      const float c3 = c2 * c1 - s2 * s1, s3 = c2 * s1 + s2 * c1;
      float2 w1 = make_float2(c1 * v1.x - s1 * v1.y, c1 * v1.y + s1 * v1.x);
      float2 w2 = make_float2(c2 * v2.x - s2 * v2.y, c2 * v2.y + s2 * v2.x);
      float2 w3 = make_float2(c3 * v3.x - s3 * v3.y, c3 * v3.y + s3 * v3.x);
      float2 t0 = make_float2(v0.x + w2.x, v0.y + w2.y);
      float2 t2 = make_float2(v0.x - w2.x, v0.y - w2.y);
      float2 t1 = make_float2(w1.x + w3.x, w1.y + w3.y);
      float2 t3 = make_float2(w1.x - w3.x, w1.y - w3.y);
      const float jx = -t3.y, jy = t3.x;  // +i*t3
      X[swz(a0)] = make_float2(t0.x + t1.x, t0.y + t1.y);
      X[swz(a0 + m)] = make_float2(t2.x + jx, t2.y + jy);
      X[swz(a0 + 2 * m)] = make_float2(t0.x - t1.x, t0.y - t1.y);
      X[swz(a0 + 3 * m)] = make_float2(t2.x - jx, t2.y - jy);
    }
    __syncthreads();
  }
}

// ---------------------------------------------------------------------------
// corr + softmax-exp, layout [B,C,T]. Writes bf16 UNNORMALIZED WEIGHTS
// wT = exp(corr - M) (32 MB) + Iv = 1/sum. wT is a DISTINCT buffer (xlo).
// ---------------------------------------------------------------------------
__global__ __launch_bounds__(256)
void corr_fft_kernel(const float* qT, const float* kT, unsigned short* __restrict__ wT,
                     float* __restrict__ Iv) {
  __shared__ float2 bA[2048];
  __shared__ float2 bB[2048];
  __shared__ float2 tw[512];
  __shared__ float2 red[4];
  const int tid = threadIdx.x;
  const int wave = tid >> 6, lane = tid & 63;
  const int b = blockIdx.y;
  const int c0 = blockIdx.x * 2;
  const float* q0 = qT + ((size_t)b * C_DIM + c0) * T_DIM;
  const float* k0p = kT + ((size_t)b * C_DIM + c0) * T_DIM;

  // twiddle table tw[j] = (cos,sin)(2*pi*j/2048), stored swizzled
#pragma unroll
  for (int jj = 0; jj < 2; jj++) {
    int j = tid + jj * 256;
    float sA, cA;
    __sincosf((float)j * (6.283185307179586f / 2048.0f), &sA, &cA);
    tw[swz(j)] = make_float2(cA, sA);
  }

  // load packed zq = q_c0 + i*q_{c0+1}; zk likewise
#pragma unroll
  for (int jj = 0; jj < 8; jj++) {
    int t = tid + jj * 256;
    bA[swz(t)] = make_float2(q0[t], q0[t + T_DIM]);
    bB[swz(t)] = make_float2(k0p[t], k0p[t + T_DIM]);
  }
  __syncthreads();

  fft_dif(bA, tw, tid, -1.0f);   // FQ, digit-reversed, in place
  fft_dif(bB, tw, tid, -1.0f);   // FK, digit-reversed, in place

  // pointwise over Hermitian pairs (f, 2048-f)
#pragma unroll 1
  for (int f = tid; f <= 1024; f += 256) {
    const int g = (2048 - f) & 2047;
    const int p = swz(enc11(f));
    const int p2 = swz(enc11(g));
    float2 Zq = bA[p], Zq2 = bA[p2];
    float2 Zk = bB[p], Zk2 = bB[p2];
    float2 Aq = make_float2(0.5f * (Zq.x + Zq2.x), 0.5f * (Zq.y - Zq2.y));
    float2 Dq = make_float2(Zq.x - Zq2.x, Zq.y + Zq2.y);
    float2 Bq = make_float2(0.5f * Dq.y, -0.5f * Dq.x);
    float2 Ak = make_float2(0.5f * (Zk.x + Zk2.x), 0.5f * (Zk.y - Zk2.y));
    float2 Dk = make_float2(Zk.x - Zk2.x, Zk.y + Zk2.y);
    float2 Bk = make_float2(0.5f * Dk.y, -0.5f * Dk.x);
    float2 G = make_float2(Aq.x * Ak.x + Aq.y * Ak.y, Aq.y * Ak.x - Aq.x * Ak.y);
    float2 H = make_float2(Bq.x * Bk.x + Bq.y * Bk.y, Bq.y * Bk.x - Bq.x * Bk.y);
    bA[p] = make_float2(G.x - H.y, G.y + H.x);
    if (p2 != p) bA[p2] = make_float2(G.x + H.y, -G.y + H.x);
  }
  __syncthreads();

  fft_dit_inv(bA, tw, tid);      // natural order, unnormalized

  // epilogue: max (raw), then exp+sum+store bf16 weights
  unsigned short* o0 = wT + ((size_t)b * C_DIM + c0) * T_DIM;
  const float sc = 1.0f / 2048.0f;
  float mx0 = -INFINITY, mx1 = -INFINITY;
#pragma unroll
  for (int jj = 0; jj < 8; jj++) {
    int t = tid + jj * 256;
    float2 o = bA[swz(t)];
    mx0 = fmaxf(mx0, o.x);
    mx1 = fmaxf(mx1, o.y);
  }
#pragma unroll
  for (int off = 32; off > 0; off >>= 1) {
    mx0 = fmaxf(mx0, __shfl_down(mx0, off));
    mx1 = fmaxf(mx1, __shfl_down(mx1, off));
  }
  if (lane == 0) red[wave] = make_float2(mx0, mx1);
  __syncthreads();
  const float M0 = fmaxf(fmaxf(red[0].x, red[1].x), fmaxf(red[2].x, red[3].x));
  const float M1 = fmaxf(fmaxf(red[0].y, red[1].y), fmaxf(red[2].y, red[3].y));
  __syncthreads();
  float s0 = 0.f, s1 = 0.f;
#pragma unroll
  for (int jj = 0; jj < 8; jj++) {
    int t = tid + jj * 256;
    float2 o = bA[swz(t)];
    float e0 = __expf((o.x - M0) * sc);
    float e1 = __expf((o.y - M1) * sc);
    s0 += e0;
    s1 += e1;
    o0[t] = f2bf(e0);
    o0[t + T_DIM] = f2bf(e1);
  }
#pragma unroll
  for (int off = 32; off > 0; off >>= 1) {
    s0 += __shfl_down(s0, off);
    s1 += __shfl_down(s1, off);
  }
  if (lane == 0) red[wave] = make_float2(s0, s1);
  __syncthreads();
  if (tid == 0) {
    float S0 = red[0].x + red[1].x + red[2].x + red[3].x;
    float S1 = red[0].y + red[1].y + red[2].y + red[3].y;
    Iv[(size_t)b * C_DIM + c0] = 1.0f / S0;
    Iv[(size_t)b * C_DIM + c0 + 1] = 1.0f / S1;
  }
}

// ---------------------------------------------------------------------------
// FUSED attn + LN1: reads bf16 weights wT [B,C,T], Iv, sv, x.
// att[t][c] = bf2f(wT[b,c,t]) * I[c]; val = x + att*sv[t]; row LN over c.
// Writes x1 as bf16 ONLY (residual carried bf16).
// ---------------------------------------------------------------------------
__global__ __launch_bounds__(512)
void attn_ln_kernel(const unsigned short* __restrict__ wT, const float* __restrict__ Iv,
                    const float* __restrict__ sv, const float* __restrict__ x,
                    const float* __restrict__ g, const float* __restrict__ be,
                    unsigned short* __restrict__ outb) {
  __shared__ float att[32][1028];   // pad 1028: 16B-aligned float4 rows
  const int tid = threadIdx.x;
  const int b = blockIdx.y;
  const int t0 = blockIdx.x * 32;

  // phase 1: gather-transpose. lanes sweep t (64B contiguous per c-row).
  const int tx = tid & 31;           // t-local
  const int cy = tid >> 5;           // 0..15
  const unsigned short* cb = wT + (size_t)b * C_DIM * T_DIM + t0 + tx;
  const float* Ib = Iv + (size_t)b * C_DIM;
#pragma unroll 8
  for (int it = 0; it < 64; ++it) {
    const int c = cy + (it << 4);
    att[tx][c] = bf2f(cb[(size_t)c * T_DIM]) * Ib[c];
  }
  __syncthreads();

  // phase 2: x + att*sv, LN stats in the same pass (val stored back to LDS)
  const int t = tid >> 4;            // 0..31
  const int l16 = tid & 15;
  const float svv = sv[(size_t)b * T_DIM + t0 + t];
  const float* xr = x + ((size_t)b * T_DIM + t0 + t) * C_DIM;
  float s = 0.f, s2 = 0.f;
#pragma unroll
  for (int j = 0; j < 16; ++j) {
    const int c = (l16 + (j << 4)) << 2;
    float4 xv = *(const float4*)(xr + c);
    float4 av = *(const float4*)&att[t][c];
    float v0 = xv.x + av.x * svv;
    float v1 = xv.y + av.y * svv;
    float v2 = xv.z + av.z * svv;
    float v3 = xv.w + av.w * svv;
    *(float4*)&att[t][c] = make_float4(v0, v1, v2, v3);
    s += v0 + v1 + v2 + v3;
    s2 += v0 * v0 + v1 * v1 + v2 * v2 + v3 * v3;
  }
  // xor-butterfly within the 16-lane group -> every lane has full sums
#pragma unroll
  for (int off = 8; off > 0; off >>= 1) {
    s += __shfl_xor(s, off);
    s2 += __shfl_xor(s2, off);
  }
  const float mu = s * (1.0f / C_DIM);
  const float var = s2 * (1.0f / C_DIM) - mu * mu;
  const float rs = rsqrtf(var + LN_EPS);
  unsigned short* obrow = outb + ((size_t)b * T_DIM + t0 + t) * C_DIM;
#pragma unroll
  for (int j = 0; j < 16; ++j) {
    const int c = (l16 + (j << 4)) << 2;
    float4 val = *(const float4*)&att[t][c];
    float4 gv = *(const float4*)(g + c);
    float4 bev = *(const float4*)(be + c);
    float o0 = (val.x - mu) * rs * gv.x + bev.x;
    float o1 = (val.y - mu) * rs * gv.y + bev.y;
    float o2 = (val.z - mu) * rs * gv.z + bev.z;
    float o3 = (val.w - mu) * rs * gv.w + bev.w;
    *(ushort4*)(obrow + c) = make_ushort4(f2bf(o0), f2bf(o1), f2bf(o2), f2bf(o3));
  }
}

// ---------------------------------------------------------------------------
// out = LayerNorm(bf16(A) + bf16(Bv)) * g + be. Final LN: A = x1, Bv = h2.
// ---------------------------------------------------------------------------
__global__ __launch_bounds__(256)
void add_ln_bb_kernel(const unsigned short* __restrict__ A, const unsigned short* __restrict__ Bv,
                      const float* __restrict__ g, const float* __restrict__ be,
                      float* __restrict__ outf) {
  const int r = blockIdx.x;
  const int tid = threadIdx.x;
  const size_t base = (size_t)r * C_DIM + (tid << 2);
  ushort4 a4 = *(const ushort4*)(A + base);
  ushort4 b4 = *(const ushort4*)(Bv + base);
  float x0 = bf2f(a4.x) + bf2f(b4.x);
  float x1 = bf2f(a4.y) + bf2f(b4.y);
  float x2 = bf2f(a4.z) + bf2f(b4.z);
  float x3 = bf2f(a4.w) + bf2f(b4.w);
  float s = x0 + x1 + x2 + x3;
  float s2 = x0 * x0 + x1 * x1 + x2 * x2 + x3 * x3;
#pragma unroll
  for (int off = 32; off > 0; off >>= 1) {
    s += __shfl_down(s, off);
    s2 += __shfl_down(s2, off);
  }
  __shared__ float ps[4], ps2[4];
  if ((tid & 63) == 0) { ps[tid >> 6] = s; ps2[tid >> 6] = s2; }
  __syncthreads();
  float S = ps[0] + ps[1] + ps[2] + ps[3];
  float S2 = ps2[0] + ps2[1] + ps2[2] + ps2[3];
  const float mu = S * (1.0f / C_DIM);
  const float var = S2 * (1.0f / C_DIM) - mu * mu;
  const float rs = rsqrtf(var + LN_EPS);
  float4 gv = *(const float4*)(g + (tid << 2));
  float4 bev = *(const float4*)(be + (tid << 2));
  float o0 = (x0 - mu) * rs * gv.x + bev.x;
  float o1 = (x1 - mu) * rs * gv.y + bev.y;
  float o2 = (x2 - mu) * rs * gv.z + bev.z;
  float o3 = (x3 - mu) * rs * gv.w + bev.w;
  *(float4*)(outf + base) = make_float4(o0, o1, o2, o3);
}

// ---------------------------------------------------------------------------
extern "C" void kernel_launch(void* const* d_in, const int* in_sizes, int n_in,
                              void* d_out, int out_size, void* d_ws, size_t ws_size,
                              hipStream_t stream) {
  const float* x   = (const float*)d_in[0];
  const float* Wq  = (const float*)d_in[1];
  const float* bq  = (const float*)d_in[2];
  const float* Wk  = (const float*)d_in[3];
  const float* bk  = (const float*)d_in[4];
  const float* Wv  = (const float*)d_in[5];
  const float* bv  = (const float*)d_in[6];
  const float* g1  = (const float*)d_in[7];
  const float* be1 = (const float*)d_in[8];
  const float* W1  = (const float*)d_in[9];
  const float* bf1 = (const float*)d_in[10];
  const float* W2  = (const float*)d_in[11];
  const float* bf2 = (const float*)d_in[12];
  const float* g2  = (const float*)d_in[13];
  const float* be2 = (const float*)d_in[14];
  float* out = (float*)d_out;

  // Workspace: qbuf(64M) kbuf(64M) xhi(32M) xlo(32M) wA(2M) wB(2M) + small
  float* ws = (float*)d_ws;
  float* qbuf = ws;                                   // qT -> (free)
  float* kbuf = ws + FSZ;                             // kT -> h2 bf16
  unsigned short* xhi = (unsigned short*)(ws + 2 * FSZ);  // x_hi f16 -> x1 bf16
  unsigned short* xlo = xhi + FSZ;                        // x_lo f16 -> wT bf16 -> h1 bf16
  unsigned short* wA = xlo + FSZ;                     // 1M half/bf16
  unsigned short* wB = wA + (size_t)C_DIM * C_DIM;    // 1M half/bf16
  float* sv = (float*)(wB + (size_t)C_DIM * C_DIM);   // [B*T]
  float* wvsum = sv + BT_DIM;                         // [C]
  float* bvsum = wvsum + C_DIM;                       // [1]
  float* Iv = bvsum + 1;                              // [B*C]
  unsigned short* h2b = (unsigned short*)kbuf;        // h2 bf16 (kT dead after corr)

  const dim3 blk(256);
  const dim3 qkgrid(C_DIM / 128, BT_DIM / 256);       // (8, 64): 256x128 tiles
  const dim3 tgrid(C_DIM / 32, C_DIM / 32);           // (32, 32)

  // Wv rowsum first (needed by fused cvt+sv)
  wv_rowsum_kernel<<<dim3(C_DIM + 1), blk, 0, stream>>>(Wv, bv, wvsum, bvsum);

  // x -> (hi, lo) f16 + sv in ONE pass over x
  cvt_split_sv_kernel<<<dim3(BT_DIM), blk, 0, stream>>>(x, wvsum, bvsum, xhi, xlo, sv);

  // qT,kT = (x @ Wq/Wk + b)^T per batch — round-4 proven schedule
  wtrans_f16_kernel<<<tgrid, blk, 0, stream>>>(Wq, wA, C_DIM, C_DIM);
  wtrans_f16_kernel<<<tgrid, blk, 0, stream>>>(Wk, wB, C_DIM, C_DIM);
  gemm_qkT_f16_8ph_kernel<<<qkgrid, dim3(512), 0, stream>>>(
      (const _Float16*)xhi, (const _Float16*)xlo,
      (const _Float16*)wA, (const _Float16*)wB,
      bq, bk, qbuf, kbuf, C_DIM, C_DIM);

  // corr + softmax-exp: bf16 weights -> xlo (x_lo f16 is dead after qkT), Iv stats
  corr_fft_kernel<<<dim3(C_DIM / 2, B_DIM), blk, 0, stream>>>(qbuf, kbuf, xlo, Iv);

  // FUSED attn + LN1: x1 bf16 -> xhi (x_hi f16 dead after qkT)
  attn_ln_kernel<<<dim3(T_DIM / 32, B_DIM), dim3(512), 0, stream>>>(
      xlo, Iv, sv, x, g1, be1, xhi);

  // FFN weights (plain bf16, transposed)
  wtrans_kernel<<<tgrid, blk, 0, stream>>>(W1, wA, C_DIM, C_DIM);
  wtrans_kernel<<<tgrid, blk, 0, stream>>>(W2, wB, C_DIM, C_DIM);

  // h1 = relu(x1 @ W1 + bf1) -> bf16 (xlo)   [8-phase 256x128, 2 blocks/CU]
  gemm_bf16_8ph_kernel<<<qkgrid, dim3(512), 0, stream>>>(
      (const __bf16*)xhi, (const __bf16*)wA, bf1, xlo, C_DIM, C_DIM, 1);
  // h2 = h1 @ W2 + bf2 -> bf16 (kbuf region)
  gemm_bf16_8ph_kernel<<<qkgrid, dim3(512), 0, stream>>>(
      (const __bf16*)xlo, (const __bf16*)wB, bf2, h2b, C_DIM, C_DIM, 0);

  // out = LN(x1(bf16) + h2(bf16))
  add_ln_bb_kernel<<<dim3(BT_DIM), blk, 0, stream>>>(xhi, h2b, g2, be2, out);
}

// Round 7
// 498.274 us; speedup vs baseline: 1.0491x; 1.0491x over previous
//
#include <hip/hip_runtime.h>
#include <math.h>

// Problem constants (fixed-shape: B=8, T=2048, C=1024, fp32 in/out)
#define B_DIM 8
#define T_DIM 2048
#define C_DIM 1024
#define BT_DIM (B_DIM * T_DIM)                 // 16384 rows
#define FSZ ((size_t)BT_DIM * C_DIM)           // 16,777,216 elements per [B,T,C]
#define LN_EPS 1e-5f

typedef __bf16 bf16x8 __attribute__((ext_vector_type(8)));
typedef _Float16 f16x8 __attribute__((ext_vector_type(8)));
typedef float f32x4 __attribute__((ext_vector_type(4)));

__device__ __forceinline__ unsigned short f2bf(float f) {
  __bf16 h = (__bf16)f;
  return __builtin_bit_cast(unsigned short, h);
}
__device__ __forceinline__ unsigned short f2h(float f) {
  _Float16 h = (_Float16)f;
  return __builtin_bit_cast(unsigned short, h);
}
__device__ __forceinline__ float bf2f(unsigned short u) {
  unsigned int v = ((unsigned int)u) << 16;
  return __builtin_bit_cast(float, v);
}
__device__ __forceinline__ float h2f(unsigned short u) {
  _Float16 h = __builtin_bit_cast(_Float16, u);
  return (float)h;
}

// async global->LDS, 16 B per lane. LDS dest must be wave-uniform base + lane*16.
__device__ __forceinline__ void gld16(const void* g, void* l) {
  __builtin_amdgcn_global_load_lds(
      (const __attribute__((address_space(1))) unsigned int*)g,
      (__attribute__((address_space(3))) unsigned int*)l, 16, 0, 0);
}

// LDS bank swizzle for float2 arrays: bank-pair = idx mod 16. XOR low 4 bits
// with a hash of higher bits -> butterfly strides {512,128,32,8,2} land on
// distinct bank pairs; contiguous access stays conflict-free (in-block perm).
__device__ __forceinline__ int swz(int a) {
  return a ^ (((a >> 4) ^ (a >> 8)) & 15);
}

// digit-reversal map of the radix-4^5 x 2 DIF: frequency f -> storage pos.
__device__ __forceinline__ int enc11(int f) {
  return ((f & 3) << 9) | (((f >> 2) & 3) << 7) | (((f >> 4) & 3) << 5) |
         (((f >> 6) & 3) << 3) | (((f >> 8) & 3) << 1) | ((f >> 10) & 1);
}

// ---------------------------------------------------------------------------
// FUSED: x fp32 -> (hi, lo) f16 split  AND  sv[r] = dot(x[r,:], wvsum)+bvsum.
// ---------------------------------------------------------------------------
__global__ __launch_bounds__(256)
void cvt_split_sv_kernel(const float* __restrict__ x, const float* __restrict__ wvsum,
                         const float* __restrict__ bvsum,
                         unsigned short* __restrict__ hi, unsigned short* __restrict__ lo,
                         float* __restrict__ sv) {
  const int r = blockIdx.x;
  const int tid = threadIdx.x;
  const size_t base = (size_t)r * C_DIM + (tid << 2);
  float4 v = *(const float4*)(x + base);
  float4 w = *(const float4*)(wvsum + (tid << 2));
  float f[4] = {v.x, v.y, v.z, v.w};
  unsigned short hv[4], lv[4];
#pragma unroll
  for (int i = 0; i < 4; i++) {
    _Float16 hb = (_Float16)f[i];
    hv[i] = __builtin_bit_cast(unsigned short, hb);
    lv[i] = f2h(f[i] - (float)hb);
  }
  *(ushort4*)(hi + base) = make_ushort4(hv[0], hv[1], hv[2], hv[3]);
  *(ushort4*)(lo + base) = make_ushort4(lv[0], lv[1], lv[2], lv[3]);
  float s = v.x * w.x + v.y * w.y + v.z * w.z + v.w * w.w;
#pragma unroll
  for (int off = 32; off > 0; off >>= 1) s += __shfl_down(s, off);
  __shared__ float ps[4];
  if ((tid & 63) == 0) ps[tid >> 6] = s;
  __syncthreads();
  if (tid == 0) sv[r] = ps[0] + ps[1] + ps[2] + ps[3] + bvsum[0];
}

// ---------------------------------------------------------------------------
// W [K,N] fp32 -> Wt [N,K] f16. 32x32 LDS tiles.
// ---------------------------------------------------------------------------
__global__ __launch_bounds__(256)
void wtrans_f16_kernel(const float* __restrict__ W, unsigned short* __restrict__ Wt,
                       int K, int N) {
  __shared__ float tile[32][33];
  const int tid = threadIdx.x;
  const int tx = tid & 31, ty = tid >> 5;
  const int n0 = blockIdx.x * 32, k0 = blockIdx.y * 32;
#pragma unroll
  for (int i = 0; i < 4; i++) {
    int row = ty + i * 8;
    tile[row][tx] = W[(size_t)(k0 + row) * N + n0 + tx];
  }
  __syncthreads();
#pragma unroll
  for (int i = 0; i < 4; i++) {
    int row = ty + i * 8;
    Wt[(size_t)(n0 + row) * K + k0 + tx] = f2h(tile[tx][row]);
  }
}

// ---------------------------------------------------------------------------
// W [K,N] fp32 -> Wt [N,K] bf16. For the FFN weights.
// ---------------------------------------------------------------------------
__global__ __launch_bounds__(256)
void wtrans_kernel(const float* __restrict__ W, unsigned short* __restrict__ Wt,
                   int K, int N) {
  __shared__ float tile[32][33];
  const int tid = threadIdx.x;
  const int tx = tid & 31, ty = tid >> 5;
  const int n0 = blockIdx.x * 32, k0 = blockIdx.y * 32;
#pragma unroll
  for (int i = 0; i < 4; i++) {
    int row = ty + i * 8;
    tile[row][tx] = W[(size_t)(k0 + row) * N + n0 + tx];
  }
  __syncthreads();
#pragma unroll
  for (int i = 0; i < 4; i++) {
    int row = ty + i * 8;
    Wt[(size_t)(n0 + row) * K + k0 + tx] = f2bf(tile[tx][row]);
  }
}

// ---------------------------------------------------------------------------
// wvsum[k] = sum_n Wv[k,n]  (blocks 0..K-1); block K reduces bv -> bvsum.
// ---------------------------------------------------------------------------
__global__ __launch_bounds__(256)
void wv_rowsum_kernel(const float* __restrict__ Wv, const float* __restrict__ bv,
                      float* __restrict__ wvsum, float* __restrict__ bvsum) {
  const int r = blockIdx.x;
  const int tid = threadIdx.x;
  const float* src = (r < C_DIM) ? (Wv + (size_t)r * C_DIM) : bv;
  float4 t4 = *(const float4*)(src + (tid << 2));
  float s = t4.x + t4.y + t4.z + t4.w;
#pragma unroll
  for (int off = 32; off > 0; off >>= 1) s += __shfl_down(s, off);
  __shared__ float ps[4];
  if ((tid & 63) == 0) ps[tid >> 6] = s;
  __syncthreads();
  if (tid == 0) {
    float v = ps[0] + ps[1] + ps[2] + ps[3];
    if (r < C_DIM) wvsum[r] = v; else bvsum[0] = v;
  }
}

// ---------------------------------------------------------------------------
// bf16 MFMA GEMM (m97 128^2 structure, RESTORED from r4: the 8-phase 256x128
// port regressed +13 us in r6 — at 2 blocks/CU its barrier phases interfere;
// this kernel's 3-4 blocks/CU implicit overlap wins). XCD-aware remap.
// ---------------------------------------------------------------------------
__global__ __launch_bounds__(256, 2)
void gemm_bf16_kernel(const __bf16* __restrict__ A, const __bf16* __restrict__ Bt,
                      const float* __restrict__ bias, float* Yf, unsigned short* Yb,
                      int K, int N, int do_relu) {
  __shared__ __align__(16) __bf16 As[128 * 32];
  __shared__ __align__(16) __bf16 Bs[128 * 32];
  const int tid = threadIdx.x;
  const int wave = tid >> 6, lane = tid & 63;
  const int wr = wave >> 1, wc = wave & 1;
  const int r15 = lane & 15, kq = lane >> 4;
  // grid (8,128): hw id = bx + 8*by; xcd = id&7. Bijective remap.
  const int h = blockIdx.y * 8 + blockIdx.x;
  const int xcd = h & 7, s = h >> 3;
  const int mIdx = (xcd << 4) + (s & 7) + ((s >> 6) << 3);
  const int nIdx = (s >> 3) & 7;
  const int m0 = mIdx * 128, n0 = nIdx * 128;

  f32x4 acc[4][4] = {};

  for (int k0 = 0; k0 < K; k0 += 32) {
#pragma unroll
    for (int r = 0; r < 2; ++r) {
      int idx = r * 256 + tid;
      int row = idx >> 2;
      int ko = (idx & 3) ^ ((row >> 1) & 3);
      gld16(A + (size_t)(m0 + row) * K + k0 + ko * 8, &As[idx * 8]);
      gld16(Bt + (size_t)(n0 + row) * K + k0 + ko * 8, &Bs[idx * 8]);
    }
    __syncthreads();
    bf16x8 afr[4], bfr[4];
#pragma unroll
    for (int i = 0; i < 4; i++) {
      int ar = wr * 64 + i * 16 + r15;
      afr[i] = *(const bf16x8*)&As[(ar * 4 + (kq ^ ((ar >> 1) & 3))) * 8];
      int br = wc * 64 + i * 16 + r15;
      bfr[i] = *(const bf16x8*)&Bs[(br * 4 + (kq ^ ((br >> 1) & 3))) * 8];
    }
#pragma unroll
    for (int mi = 0; mi < 4; mi++)
#pragma unroll
      for (int ni = 0; ni < 4; ni++)
        acc[mi][ni] = __builtin_amdgcn_mfma_f32_16x16x32_bf16(afr[mi], bfr[ni], acc[mi][ni], 0, 0, 0);
    __syncthreads();
  }

  float bv[4];
#pragma unroll
  for (int ni = 0; ni < 4; ni++) bv[ni] = bias[n0 + wc * 64 + ni * 16 + r15];

#pragma unroll
  for (int mi = 0; mi < 4; mi++)
#pragma unroll
    for (int ni = 0; ni < 4; ni++) {
      const int n = n0 + wc * 64 + ni * 16 + r15;
#pragma unroll
      for (int r = 0; r < 4; r++) {
        const int m = m0 + wr * 64 + mi * 16 + kq * 4 + r;
        float v = acc[mi][ni][r] + bv[ni];
        if (do_relu) v = fmaxf(v, 0.f);
        if (Yf) Yf[(size_t)m * N + n] = v;
        if (Yb) Yb[(size_t)m * N + n] = f2bf(v);
      }
    }
}

// ---------------------------------------------------------------------------
// FUSED q+k split-f16 GEMM with TRANSPOSED outputs: Yq/Yk [B,C,T] now F16
// (halves qkT write traffic and corr_fft read traffic; f16 rel-err ~5e-4 is
// an order below the bf16 wT store already in the pipeline).
// Schedule = round-4 proven 4-phase per-phase-barrier (139.5 us, conflicts 0).
// ---------------------------------------------------------------------------
__global__ __launch_bounds__(512, 2)
void gemm_qkT_f16_8ph_kernel(const _Float16* __restrict__ Ahi, const _Float16* __restrict__ Alo,
                             const _Float16* __restrict__ Bq, const _Float16* __restrict__ Bk,
                             const float* __restrict__ biasq, const float* __restrict__ biask,
                             unsigned short* __restrict__ Yq, unsigned short* __restrict__ Yk,
                             int K, int N) {
  // 3-ring LDS: (16+16+8+8) KB * 3 = 144 KB -> 1 block/CU
  __shared__ __align__(16) _Float16 AhL[3][256 * 32];
  __shared__ __align__(16) _Float16 AlL[3][256 * 32];
  __shared__ __align__(16) _Float16 BqL[3][128 * 32];
  __shared__ __align__(16) _Float16 BkL[3][128 * 32];

  const int tid = threadIdx.x;
  const int wave = tid >> 6, lane = tid & 63;
  const int wr = wave >> 2, wc = wave & 3;          // 2 x 4 wave grid
  const int r15 = lane & 15, kq = lane >> 4;
  // grid (8,64): hw id = bx + 8*by; xcd = id&7. Bijective remap.
  const int h = blockIdx.y * 8 + blockIdx.x;
  const int xcd = h & 7, s = h >> 3;
  const int mIdx = (xcd << 3) + (s & 3) + ((s >> 5) << 2);
  const int nIdx = (s >> 2) & 7;
  const int m0 = mIdx * 256, n0 = nIdx * 128;
  const int NT = K >> 5;                            // 32 K-tiles of BK=32

  // --- staging descriptors ---
  const int row_a0 = tid >> 2;                      // 0..127
  const int row_a1 = row_a0 + 128;                  // 128..255
  const int ch = tid & 3;
  const int ko0 = ch ^ ((row_a0 >> 1) & 3);
  const int ko1 = ch ^ ((row_a1 >> 1) & 3);
  const _Float16* agh0 = Ahi + (size_t)(m0 + row_a0) * K + ko0 * 8;
  const _Float16* agl0 = Alo + (size_t)(m0 + row_a0) * K + ko0 * 8;
  const _Float16* agh1 = Ahi + (size_t)(m0 + row_a1) * K + ko1 * 8;
  const _Float16* agl1 = Alo + (size_t)(m0 + row_a1) * K + ko1 * 8;
  const _Float16* bgq  = Bq  + (size_t)(n0 + row_a0) * K + ko0 * 8;
  const _Float16* bgk  = Bk  + (size_t)(n0 + row_a0) * K + ko0 * 8;

  // --- fragment read offsets ---
  const int ksel = kq ^ ((r15 >> 1) & 3);
  const int aoff = (wr * 128 + r15) * 32 + ksel * 8;   // + mi*512
  const int boff = (wc * 32 + r15) * 32 + ksel * 8;    // + ni*512

  f32x4 accq[8][2] = {};
  f32x4 acck[8][2] = {};

  // --- prologue: stage tile 0 -> buf0, tile 1 -> buf1 (6 loads each) ---
  gld16(agh0 + 0, &AhL[0][(size_t)tid * 8]);
  gld16(agl0 + 0, &AlL[0][(size_t)tid * 8]);
  gld16(agh1 + 0, &AhL[0][(size_t)(tid + 512) * 8]);
  gld16(agl1 + 0, &AlL[0][(size_t)(tid + 512) * 8]);
  gld16(bgq + 0, &BqL[0][(size_t)tid * 8]);
  gld16(bgk + 0, &BkL[0][(size_t)tid * 8]);
  gld16(agh0 + 32, &AhL[1][(size_t)tid * 8]);
  gld16(agl0 + 32, &AlL[1][(size_t)tid * 8]);
  gld16(agh1 + 32, &AhL[1][(size_t)(tid + 512) * 8]);
  gld16(agl1 + 32, &AlL[1][(size_t)(tid + 512) * 8]);
  gld16(bgq + 32, &BqL[1][(size_t)tid * 8]);
  gld16(bgk + 32, &BkL[1][(size_t)tid * 8]);

  int bR = 0;  // read buffer = j % 3
  int bS = 2;  // stage buffer = (j+2) % 3

  for (int j = 0; j < NT; ++j) {
    // Tile-j data ready: newest 6 outstanding loads belong to tile j+1.
    if (j < NT - 1) {
      asm volatile("s_waitcnt vmcnt(6)" ::: "memory");
    } else {
      asm volatile("s_waitcnt vmcnt(0)" ::: "memory");
    }
    __builtin_amdgcn_s_barrier();
    __builtin_amdgcn_sched_barrier(0);

    const int kk = (j + 2) * 32;
    const bool doStage = (j + 2 < NT);

    // B fragments for the whole tile (phase 0 ds-reads)
    f16x8 bqf[2], bkf[2];
#pragma unroll
    for (int ni = 0; ni < 2; ++ni) {
      bqf[ni] = *(const f16x8*)&BqL[bR][boff + ni * 512];
      bkf[ni] = *(const f16x8*)&BkL[bR][boff + ni * 512];
    }

#pragma unroll
    for (int p = 0; p < 4; ++p) {
      f16x8 ah0 = *(const f16x8*)&AhL[bR][aoff + (2 * p + 0) * 512];
      f16x8 al0 = *(const f16x8*)&AlL[bR][aoff + (2 * p + 0) * 512];
      f16x8 ah1 = *(const f16x8*)&AhL[bR][aoff + (2 * p + 1) * 512];
      f16x8 al1 = *(const f16x8*)&AlL[bR][aoff + (2 * p + 1) * 512];
      if (doStage) {
        if (p == 0) {
          gld16(agh0 + kk, &AhL[bS][(size_t)tid * 8]);
          gld16(agl0 + kk, &AlL[bS][(size_t)tid * 8]);
        }
        if (p == 1) {
          gld16(agh1 + kk, &AhL[bS][(size_t)(tid + 512) * 8]);
          gld16(agl1 + kk, &AlL[bS][(size_t)(tid + 512) * 8]);
        }
        if (p == 2) gld16(bgq + kk, &BqL[bS][(size_t)tid * 8]);
        if (p == 3) gld16(bgk + kk, &BkL[bS][(size_t)tid * 8]);
      }
      __builtin_amdgcn_s_barrier();                       // phase alignment
      asm volatile("s_waitcnt lgkmcnt(0)" ::: "memory");  // own ds_reads done
      __builtin_amdgcn_sched_barrier(0);                  // rule 18: pin MFMA below
      __builtin_amdgcn_s_setprio(1);
#pragma unroll
      for (int m2 = 0; m2 < 2; ++m2) {
        const int mi = 2 * p + m2;
        const f16x8 ahv = m2 ? ah1 : ah0;
        const f16x8 alv = m2 ? al1 : al0;
#pragma unroll
        for (int ni = 0; ni < 2; ++ni) {
          accq[mi][ni] = __builtin_amdgcn_mfma_f32_16x16x32_f16(ahv, bqf[ni], accq[mi][ni], 0, 0, 0);
          accq[mi][ni] = __builtin_amdgcn_mfma_f32_16x16x32_f16(alv, bqf[ni], accq[mi][ni], 0, 0, 0);
          acck[mi][ni] = __builtin_amdgcn_mfma_f32_16x16x32_f16(ahv, bkf[ni], acck[mi][ni], 0, 0, 0);
          acck[mi][ni] = __builtin_amdgcn_mfma_f32_16x16x32_f16(alv, bkf[ni], acck[mi][ni], 0, 0, 0);
        }
      }
      __builtin_amdgcn_s_setprio(0);
      __builtin_amdgcn_sched_barrier(0);
    }

    bR = (bR + 1 == 3) ? 0 : bR + 1;
    bS = (bS + 1 == 3) ? 0 : bS + 1;
  }

  // --- epilogue: bias + transposed f16 (ushort4 = 8B) stores ---
  float bvq[2], bvk[2];
#pragma unroll
  for (int ni = 0; ni < 2; ++ni) {
    bvq[ni] = biasq[n0 + wc * 32 + ni * 16 + r15];
    bvk[ni] = biask[n0 + wc * 32 + ni * 16 + r15];
  }

#pragma unroll
  for (int mi = 0; mi < 8; ++mi) {
    const int mbase = m0 + wr * 128 + mi * 16 + kq * 4;  // 4 consecutive m
    const int bb = mbase >> 11;                          // batch (T=2048)
    const int t = mbase & (T_DIM - 1);
#pragma unroll
    for (int ni = 0; ni < 2; ++ni) {
      const int n = n0 + wc * 32 + ni * 16 + r15;
      const size_t o = ((size_t)bb * C_DIM + n) * T_DIM + t;
      *(ushort4*)(Yq + o) = make_ushort4(
          f2h(accq[mi][ni][0] + bvq[ni]), f2h(accq[mi][ni][1] + bvq[ni]),
          f2h(accq[mi][ni][2] + bvq[ni]), f2h(accq[mi][ni][3] + bvq[ni]));
      *(ushort4*)(Yk + o) = make_ushort4(
          f2h(acck[mi][ni][0] + bvk[ni]), f2h(acck[mi][ni][1] + bvk[ni]),
          f2h(acck[mi][ni][2] + bvk[ni]), f2h(acck[mi][ni][3] + bvk[ni]));
    }
  }
}

// ---------------------------------------------------------------------------
// In-place 2048-pt FFT, radix-4 DIF (5 stages) + radix-2.
// ---------------------------------------------------------------------------
__device__ void fft_dif(float2* X, const float2* tw, int tid, float sgn) {
#pragma unroll
  for (int s = 0; s < 5; s++) {
    const int m = 512 >> (2 * s);
    const int jstep = 512 / m;  // 4^s
#pragma unroll
    for (int ii = 0; ii < 2; ii++) {
      const int i = tid + ii * 256;
      const int q = i & (m - 1);
      const int a0 = ((i - q) << 2) + q;
      float2 x0 = X[swz(a0)];
      float2 x1 = X[swz(a0 + m)];
      float2 x2 = X[swz(a0 + 2 * m)];
      float2 x3 = X[swz(a0 + 3 * m)];
      float2 t0 = make_float2(x0.x + x2.x, x0.y + x2.y);
      float2 t2 = make_float2(x0.x - x2.x, x0.y - x2.y);
      float2 t1 = make_float2(x1.x + x3.x, x1.y + x3.y);
      float2 t3 = make_float2(x1.x - x3.x, x1.y - x3.y);
      const float jx = -sgn * t3.y, jy = sgn * t3.x;   // sgn*i*t3
      float2 y0 = make_float2(t0.x + t1.x, t0.y + t1.y);
      float2 y1 = make_float2(t2.x + jx, t2.y + jy);
      float2 y2 = make_float2(t0.x - t1.x, t0.y - t1.y);
      float2 y3 = make_float2(t2.x - jx, t2.y - jy);
      const int j1 = q * jstep;
      float2 tv = tw[swz(j1)];
      const float c1 = tv.x, s1 = tv.y * sgn;
      const float c2 = c1 * c1 - s1 * s1, s2 = 2.f * c1 * s1;
      const float c3 = c2 * c1 - s2 * s1, s3 = c2 * s1 + s2 * c1;
      X[swz(a0)] = y0;
      X[swz(a0 + m)] = make_float2(c1 * y1.x - s1 * y1.y, c1 * y1.y + s1 * y1.x);
      X[swz(a0 + 2 * m)] = make_float2(c2 * y2.x - s2 * y2.y, c2 * y2.y + s2 * y2.x);
      X[swz(a0 + 3 * m)] = make_float2(c3 * y3.x - s3 * y3.y, c3 * y3.y + s3 * y3.x);
    }
    __syncthreads();
  }
  // final radix-2 on adjacent pairs, twiddle-free
#pragma unroll
  for (int ii = 0; ii < 4; ii++) {
    const int a = (tid + ii * 256) << 1;
    float2 u = X[swz(a)], v = X[swz(a + 1)];
    X[swz(a)] = make_float2(u.x + v.x, u.y + v.y);
    X[swz(a + 1)] = make_float2(u.x - v.x, u.y - v.y);
  }
  __syncthreads();
}

// In-place inverse (adjoint of fft_dif, unnormalized).
__device__ void fft_dit_inv(float2* X, const float2* tw, int tid) {
#pragma unroll
  for (int ii = 0; ii < 4; ii++) {
    const int a = (tid + ii * 256) << 1;
    float2 u = X[swz(a)], v = X[swz(a + 1)];
    X[swz(a)] = make_float2(u.x + v.x, u.y + v.y);
    X[swz(a + 1)] = make_float2(u.x - v.x, u.y - v.y);
  }
  __syncthreads();
#pragma unroll
  for (int s = 4; s >= 0; s--) {
    const int m = 512 >> (2 * s);
    const int jstep = 512 / m;
#pragma unroll
    for (int ii = 0; ii < 2; ii++) {
      const int i = tid + ii * 256;
      const int q = i & (m - 1);
      const int a0 = ((i - q) << 2) + q;
      float2 v0 = X[swz(a0)];
      float2 v1 = X[swz(a0 + m)];
      float2 v2 = X[swz(a0 + 2 * m)];
      float2 v3 = X[swz(a0 + 3 * m)];
      const int j1 = q * jstep;
      float2 tv = tw[swz(j1)];
      const float c1 = tv.x, s1 = tv.y;  // e^{+i theta}
      const float c2 = c1 * c1 - s1 * s1, s2 = 2.f * c1 * s1;
      const float c3 = c2 * c1 - s2 * s1, s3 = c2 * s1 + s2 * c1;
      float2 w1 = make_float2(c1 * v1.x - s1 * v1.y, c1 * v1.y + s1 * v1.x);
      float2 w2 = make_float2(c2 * v2.x - s2 * v2.y, c2 * v2.y + s2 * v2.x);
      float2 w3 = make_float2(c3 * v3.x - s3 * v3.y, c3 * v3.y + s3 * v3.x);
      float2 t0 = make_float2(v0.x + w2.x, v0.y + w2.y);
      float2 t2 = make_float2(v0.x - w2.x, v0.y - w2.y);
      float2 t1 = make_float2(w1.x + w3.x, w1.y + w3.y);
      float2 t3 = make_float2(w1.x - w3.x, w1.y - w3.y);
      const float jx = -t3.y, jy = t3.x;  // +i*t3
      X[swz(a0)] = make_float2(t0.x + t1.x, t0.y + t1.y);
      X[swz(a0 + m)] = make_float2(t2.x + jx, t2.y + jy);
      X[swz(a0 + 2 * m)] = make_float2(t0.x - t1.x, t0.y - t1.y);
      X[swz(a0 + 3 * m)] = make_float2(t2.x - jx, t2.y - jy);
    }
    __syncthreads();
  }
}

// ---------------------------------------------------------------------------
// corr + softmax-exp, layout [B,C,T]. INPUT qT/kT now F16 (half the reads).
// Writes bf16 unnormalized weights wT = exp(corr-M) + Iv = 1/sum.
// ---------------------------------------------------------------------------
__global__ __launch_bounds__(256)
void corr_fft_kernel(const unsigned short* qT, const unsigned short* kT,
                     unsigned short* __restrict__ wT, float* __restrict__ Iv) {
  __shared__ float2 bA[2048];
  __shared__ float2 bB[2048];
  __shared__ float2 tw[512];
  __shared__ float2 red[4];
  const int tid = threadIdx.x;
  const int wave = tid >> 6, lane = tid & 63;
  const int b = blockIdx.y;
  const int c0 = blockIdx.x * 2;
  const unsigned short* q0 = qT + ((size_t)b * C_DIM + c0) * T_DIM;
  const unsigned short* k0p = kT + ((size_t)b * C_DIM + c0) * T_DIM;

  // twiddle table tw[j] = (cos,sin)(2*pi*j/2048), stored swizzled
#pragma unroll
  for (int jj = 0; jj < 2; jj++) {
    int j = tid + jj * 256;
    float sA, cA;
    __sincosf((float)j * (6.283185307179586f / 2048.0f), &sA, &cA);
    tw[swz(j)] = make_float2(cA, sA);
  }

  // load packed zq = q_c0 + i*q_{c0+1}; zk likewise
#pragma unroll
  for (int jj = 0; jj < 8; jj++) {
    int t = tid + jj * 256;
    bA[swz(t)] = make_float2(h2f(q0[t]), h2f(q0[t + T_DIM]));
    bB[swz(t)] = make_float2(h2f(k0p[t]), h2f(k0p[t + T_DIM]));
  }
  __syncthreads();

  fft_dif(bA, tw, tid, -1.0f);   // FQ, digit-reversed, in place
  fft_dif(bB, tw, tid, -1.0f);   // FK, digit-reversed, in place

  // pointwise over Hermitian pairs (f, 2048-f)
#pragma unroll 1
  for (int f = tid; f <= 1024; f += 256) {
    const int g = (2048 - f) & 2047;
    const int p = swz(enc11(f));
    const int p2 = swz(enc11(g));
    float2 Zq = bA[p], Zq2 = bA[p2];
    float2 Zk = bB[p], Zk2 = bB[p2];
    float2 Aq = make_float2(0.5f * (Zq.x + Zq2.x), 0.5f * (Zq.y - Zq2.y));
    float2 Dq = make_float2(Zq.x - Zq2.x, Zq.y + Zq2.y);
    float2 Bq = make_float2(0.5f * Dq.y, -0.5f * Dq.x);
    float2 Ak = make_float2(0.5f * (Zk.x + Zk2.x), 0.5f * (Zk.y - Zk2.y));
    float2 Dk = make_float2(Zk.x - Zk2.x, Zk.y + Zk2.y);
    float2 Bk = make_float2(0.5f * Dk.y, -0.5f * Dk.x);
    float2 G = make_float2(Aq.x * Ak.x + Aq.y * Ak.y, Aq.y * Ak.x - Aq.x * Ak.y);
    float2 H = make_float2(Bq.x * Bk.x + Bq.y * Bk.y, Bq.y * Bk.x - Bq.x * Bk.y);
    bA[p] = make_float2(G.x - H.y, G.y + H.x);
    if (p2 != p) bA[p2] = make_float2(G.x + H.y, -G.y + H.x);
  }
  __syncthreads();

  fft_dit_inv(bA, tw, tid);      // natural order, unnormalized

  // epilogue: max (raw), then exp+sum+store bf16 weights
  unsigned short* o0 = wT + ((size_t)b * C_DIM + c0) * T_DIM;
  const float sc = 1.0f / 2048.0f;
  float mx0 = -INFINITY, mx1 = -INFINITY;
#pragma unroll
  for (int jj = 0; jj < 8; jj++) {
    int t = tid + jj * 256;
    float2 o = bA[swz(t)];
    mx0 = fmaxf(mx0, o.x);
    mx1 = fmaxf(mx1, o.y);
  }
#pragma unroll
  for (int off = 32; off > 0; off >>= 1) {
    mx0 = fmaxf(mx0, __shfl_down(mx0, off));
    mx1 = fmaxf(mx1, __shfl_down(mx1, off));
  }
  if (lane == 0) red[wave] = make_float2(mx0, mx1);
  __syncthreads();
  const float M0 = fmaxf(fmaxf(red[0].x, red[1].x), fmaxf(red[2].x, red[3].x));
  const float M1 = fmaxf(fmaxf(red[0].y, red[1].y), fmaxf(red[2].y, red[3].y));
  __syncthreads();
  float s0 = 0.f, s1 = 0.f;
#pragma unroll
  for (int jj = 0; jj < 8; jj++) {
    int t = tid + jj * 256;
    float2 o = bA[swz(t)];
    float e0 = __expf((o.x - M0) * sc);
    float e1 = __expf((o.y - M1) * sc);
    s0 += e0;
    s1 += e1;
    o0[t] = f2bf(e0);
    o0[t + T_DIM] = f2bf(e1);
  }
#pragma unroll
  for (int off = 32; off > 0; off >>= 1) {
    s0 += __shfl_down(s0, off);
    s1 += __shfl_down(s1, off);
  }
  if (lane == 0) red[wave] = make_float2(s0, s1);
  __syncthreads();
  if (tid == 0) {
    float S0 = red[0].x + red[1].x + red[2].x + red[3].x;
    float S1 = red[0].y + red[1].y + red[2].y + red[3].y;
    Iv[(size_t)b * C_DIM + c0] = 1.0f / S0;
    Iv[(size_t)b * C_DIM + c0 + 1] = 1.0f / S1;
  }
}

// ---------------------------------------------------------------------------
// FUSED attn + LN1: reads bf16 weights wT [B,C,T], Iv, sv, x.
// att[t][c] = bf2f(wT[b,c,t]) * I[c]; val = x + att*sv[t]; row LN over c.
// Writes x1 as bf16 ONLY (residual carried bf16).
// ---------------------------------------------------------------------------
__global__ __launch_bounds__(512)
void attn_ln_kernel(const unsigned short* __restrict__ wT, const float* __restrict__ Iv,
                    const float* __restrict__ sv, const float* __restrict__ x,
                    const float* __restrict__ g, const float* __restrict__ be,
                    unsigned short* __restrict__ outb) {
  __shared__ float att[32][1028];   // pad 1028: 16B-aligned float4 rows
  const int tid = threadIdx.x;
  const int b = blockIdx.y;
  const int t0 = blockIdx.x * 32;

  // phase 1: gather-transpose. lanes sweep t (64B contiguous per c-row).
  const int tx = tid & 31;           // t-local
  const int cy = tid >> 5;           // 0..15
  const unsigned short* cb = wT + (size_t)b * C_DIM * T_DIM + t0 + tx;
  const float* Ib = Iv + (size_t)b * C_DIM;
#pragma unroll 8
  for (int it = 0; it < 64; ++it) {
    const int c = cy + (it << 4);
    att[tx][c] = bf2f(cb[(size_t)c * T_DIM]) * Ib[c];
  }
  __syncthreads();

  // phase 2: x + att*sv, LN stats in the same pass (val stored back to LDS)
  const int t = tid >> 4;            // 0..31
  const int l16 = tid & 15;
  const float svv = sv[(size_t)b * T_DIM + t0 + t];
  const float* xr = x + ((size_t)b * T_DIM + t0 + t) * C_DIM;
  float s = 0.f, s2 = 0.f;
#pragma unroll
  for (int j = 0; j < 16; ++j) {
    const int c = (l16 + (j << 4)) << 2;
    float4 xv = *(const float4*)(xr + c);
    float4 av = *(const float4*)&att[t][c];
    float v0 = xv.x + av.x * svv;
    float v1 = xv.y + av.y * svv;
    float v2 = xv.z + av.z * svv;
    float v3 = xv.w + av.w * svv;
    *(float4*)&att[t][c] = make_float4(v0, v1, v2, v3);
    s += v0 + v1 + v2 + v3;
    s2 += v0 * v0 + v1 * v1 + v2 * v2 + v3 * v3;
  }
  // xor-butterfly within the 16-lane group -> every lane has full sums
#pragma unroll
  for (int off = 8; off > 0; off >>= 1) {
    s += __shfl_xor(s, off);
    s2 += __shfl_xor(s2, off);
  }
  const float mu = s * (1.0f / C_DIM);
  const float var = s2 * (1.0f / C_DIM) - mu * mu;
  const float rs = rsqrtf(var + LN_EPS);
  unsigned short* obrow = outb + ((size_t)b * T_DIM + t0 + t) * C_DIM;
#pragma unroll
  for (int j = 0; j < 16; ++j) {
    const int c = (l16 + (j << 4)) << 2;
    float4 val = *(const float4*)&att[t][c];
    float4 gv = *(const float4*)(g + c);
    float4 bev = *(const float4*)(be + c);
    float o0 = (val.x - mu) * rs * gv.x + bev.x;
    float o1 = (val.y - mu) * rs * gv.y + bev.y;
    float o2 = (val.z - mu) * rs * gv.z + bev.z;
    float o3 = (val.w - mu) * rs * gv.w + bev.w;
    *(ushort4*)(obrow + c) = make_ushort4(f2bf(o0), f2bf(o1), f2bf(o2), f2bf(o3));
  }
}

// ---------------------------------------------------------------------------
// out = LayerNorm(bf16(A) + bf16(Bv)) * g + be. Final LN: A = x1, Bv = h2.
// ---------------------------------------------------------------------------
__global__ __launch_bounds__(256)
void add_ln_bb_kernel(const unsigned short* __restrict__ A, const unsigned short* __restrict__ Bv,
                      const float* __restrict__ g, const float* __restrict__ be,
                      float* __restrict__ outf) {
  const int r = blockIdx.x;
  const int tid = threadIdx.x;
  const size_t base = (size_t)r * C_DIM + (tid << 2);
  ushort4 a4 = *(const ushort4*)(A + base);
  ushort4 b4 = *(const ushort4*)(Bv + base);
  float x0 = bf2f(a4.x) + bf2f(b4.x);
  float x1 = bf2f(a4.y) + bf2f(b4.y);
  float x2 = bf2f(a4.z) + bf2f(b4.z);
  float x3 = bf2f(a4.w) + bf2f(b4.w);
  float s = x0 + x1 + x2 + x3;
  float s2 = x0 * x0 + x1 * x1 + x2 * x2 + x3 * x3;
#pragma unroll
  for (int off = 32; off > 0; off >>= 1) {
    s += __shfl_down(s, off);
    s2 += __shfl_down(s2, off);
  }
  __shared__ float ps[4], ps2[4];
  if ((tid & 63) == 0) { ps[tid >> 6] = s; ps2[tid >> 6] = s2; }
  __syncthreads();
  float S = ps[0] + ps[1] + ps[2] + ps[3];
  float S2 = ps2[0] + ps2[1] + ps2[2] + ps2[3];
  const float mu = S * (1.0f / C_DIM);
  const float var = S2 * (1.0f / C_DIM) - mu * mu;
  const float rs = rsqrtf(var + LN_EPS);
  float4 gv = *(const float4*)(g + (tid << 2));
  float4 bev = *(const float4*)(be + (tid << 2));
  float o0 = (x0 - mu) * rs * gv.x + bev.x;
  float o1 = (x1 - mu) * rs * gv.y + bev.y;
  float o2 = (x2 - mu) * rs * gv.z + bev.z;
  float o3 = (x3 - mu) * rs * gv.w + bev.w;
  *(float4*)(outf + base) = make_float4(o0, o1, o2, o3);
}

// ---------------------------------------------------------------------------
extern "C" void kernel_launch(void* const* d_in, const int* in_sizes, int n_in,
                              void* d_out, int out_size, void* d_ws, size_t ws_size,
                              hipStream_t stream) {
  const float* x   = (const float*)d_in[0];
  const float* Wq  = (const float*)d_in[1];
  const float* bq  = (const float*)d_in[2];
  const float* Wk  = (const float*)d_in[3];
  const float* bk  = (const float*)d_in[4];
  const float* Wv  = (const float*)d_in[5];
  const float* bv  = (const float*)d_in[6];
  const float* g1  = (const float*)d_in[7];
  const float* be1 = (const float*)d_in[8];
  const float* W1  = (const float*)d_in[9];
  const float* bf1 = (const float*)d_in[10];
  const float* W2  = (const float*)d_in[11];
  const float* bf2 = (const float*)d_in[12];
  const float* g2  = (const float*)d_in[13];
  const float* be2 = (const float*)d_in[14];
  float* out = (float*)d_out;

  // Workspace: qbuf(64M) kbuf(64M) xhi(32M) xlo(32M) wA(2M) wB(2M) + small
  float* ws = (float*)d_ws;
  float* qbuf = ws;                                   // qT f16 -> (free)
  float* kbuf = ws + FSZ;                             // kT f16 -> h2 bf16
  unsigned short* xhi = (unsigned short*)(ws + 2 * FSZ);  // x_hi f16 -> x1 bf16
  unsigned short* xlo = xhi + FSZ;                        // x_lo f16 -> wT bf16 -> h1 bf16
  unsigned short* wA = xlo + FSZ;                     // 1M half/bf16
  unsigned short* wB = wA + (size_t)C_DIM * C_DIM;    // 1M half/bf16
  float* sv = (float*)(wB + (size_t)C_DIM * C_DIM);   // [B*T]
  float* wvsum = sv + BT_DIM;                         // [C]
  float* bvsum = wvsum + C_DIM;                       // [1]
  float* Iv = bvsum + 1;                              // [B*C]
  unsigned short* qTf16 = (unsigned short*)qbuf;      // qT f16 [B,C,T]
  unsigned short* kTf16 = (unsigned short*)kbuf;      // kT f16 [B,C,T]
  unsigned short* h2b = (unsigned short*)kbuf;        // h2 bf16 (kT dead after corr)

  const dim3 blk(256);
  const dim3 ggrid(C_DIM / 128, BT_DIM / 128);        // (8, 128) for FFN gemms
  const dim3 qkgrid(C_DIM / 128, BT_DIM / 256);       // (8, 64) for qkT
  const dim3 tgrid(C_DIM / 32, C_DIM / 32);           // (32, 32)

  // Wv rowsum first (needed by fused cvt+sv)
  wv_rowsum_kernel<<<dim3(C_DIM + 1), blk, 0, stream>>>(Wv, bv, wvsum, bvsum);

  // x -> (hi, lo) f16 + sv in ONE pass over x
  cvt_split_sv_kernel<<<dim3(BT_DIM), blk, 0, stream>>>(x, wvsum, bvsum, xhi, xlo, sv);

  // qT,kT = (x @ Wq/Wk + b)^T per batch — round-4 proven schedule, F16 out
  wtrans_f16_kernel<<<tgrid, blk, 0, stream>>>(Wq, wA, C_DIM, C_DIM);
  wtrans_f16_kernel<<<tgrid, blk, 0, stream>>>(Wk, wB, C_DIM, C_DIM);
  gemm_qkT_f16_8ph_kernel<<<qkgrid, dim3(512), 0, stream>>>(
      (const _Float16*)xhi, (const _Float16*)xlo,
      (const _Float16*)wA, (const _Float16*)wB,
      bq, bk, qTf16, kTf16, C_DIM, C_DIM);

  // corr + softmax-exp: f16 inputs, bf16 weights -> xlo, Iv stats
  corr_fft_kernel<<<dim3(C_DIM / 2, B_DIM), blk, 0, stream>>>(qTf16, kTf16, xlo, Iv);

  // FUSED attn + LN1: x1 bf16 -> xhi (x_hi f16 dead after qkT)
  attn_ln_kernel<<<dim3(T_DIM / 32, B_DIM), dim3(512), 0, stream>>>(
      xlo, Iv, sv, x, g1, be1, xhi);

  // FFN weights (plain bf16, transposed)
  wtrans_kernel<<<tgrid, blk, 0, stream>>>(W1, wA, C_DIM, C_DIM);
  wtrans_kernel<<<tgrid, blk, 0, stream>>>(W2, wB, C_DIM, C_DIM);

  // h1 = relu(x1 @ W1 + bf1) -> bf16 (xlo)   [m97 128^2 kernel, restored]
  gemm_bf16_kernel<<<ggrid, blk, 0, stream>>>((const __bf16*)xhi, (const __bf16*)wA,
                                              bf1, nullptr, xlo, C_DIM, C_DIM, 1);
  // h2 = h1 @ W2 + bf2 -> bf16 (kbuf region)
  gemm_bf16_kernel<<<ggrid, blk, 0, stream>>>((const __bf16*)xlo, (const __bf16*)wB,
                                              bf2, nullptr, h2b, C_DIM, C_DIM, 0);

  // out = LN(x1(bf16) + h2(bf16))
  add_ln_bb_kernel<<<dim3(BT_DIM), blk, 0, stream>>>(xhi, h2b, g2, be2, out);
}